// Round 3
// baseline (1576.191 us; speedup 1.0000x reference)
//
#include <hip/hip_runtime.h>
#include <cstdint>
#include <cstddef>

#define B_ 4
#define L_ 4096
#define H_ 1024
#define NH_ 16
#define W_ 64
#define SHIFT_ 32
#define FF_ 4096
#define HD_ 64
#define MC_ 2048  // phase chunk rows (multiple of 128; window/batch aligned)

typedef unsigned short u16;
typedef __attribute__((ext_vector_type(8))) __bf16 bf16x8;
typedef __attribute__((ext_vector_type(4))) float f32x4;
typedef __attribute__((ext_vector_type(4))) unsigned short u16x4;

__device__ __forceinline__ float bf2f(u16 u) {
    unsigned int x = ((unsigned int)u) << 16;
    float f;
    __builtin_memcpy(&f, &x, 4);
    return f;
}
__device__ __forceinline__ u16 f2bf(float f) {
    unsigned int u;
    __builtin_memcpy(&u, &f, 4);
    u = (u + 0x7fffu + ((u >> 16) & 1u)) >> 16;  // RNE
    return (u16)u;
}

__device__ __forceinline__ bf16x8 ldfrag(const u16* p) {
    uint4 v = *(const uint4*)p;  // ds_read_b128 (16B aligned)
    bf16x8 r;
    __builtin_memcpy(&r, &v, 16);
    return r;
}

__device__ __forceinline__ f32x4 mfma16(bf16x8 a, bf16x8 b, f32x4 c) {
    return __builtin_amdgcn_mfma_f32_16x16x32_bf16(a, b, c, 0, 0, 0);
}

// ---------------------------------------------------------------------------
// fp32 -> bf16 conversion (weights prologue)
// ---------------------------------------------------------------------------
__global__ __launch_bounds__(256) void cvt_kernel(
    const float* __restrict__ src, u16* __restrict__ dst, int n4) {
    const int i = blockIdx.x * 256 + threadIdx.x;
    if (i < n4) {
        const float4 v = ((const float4*)src)[i];
        u16x4 o;
        o[0] = f2bf(v.x); o[1] = f2bf(v.y);
        o[2] = f2bf(v.z); o[3] = f2bf(v.w);
        ((u16x4*)dst)[i] = o;
    }
}

// ---------------------------------------------------------------------------
// GEMM: C[M,N] = act(A[M,K]bf16 @ B[N,K]bf16^T + bias[N]f32) (+resid f32)
// 128x128 tile, BK=32, 256 threads (4 waves 2x2), explicit reg staging.
// OUTF: 0 = write bf16 (u16), 1 = write fp32 (float)
// ---------------------------------------------------------------------------
template <int GELU, int RESID, int OUTF>
__global__ __launch_bounds__(256, 2) void gemm_bt(
    const u16* __restrict__ A, const u16* __restrict__ Bm,
    const float* __restrict__ bias, const float* __restrict__ resid,
    void* __restrict__ Cv, int M, int N, int K) {
    __shared__ __align__(16) u16 lA[128 * 32];
    __shared__ __align__(16) u16 lB[128 * 32];

    const int t = threadIdx.x;
    const int lane = t & 63;
    const int wv = t >> 6;
    const int wrow = wv >> 1, wcol = wv & 1;
    const int ln15 = lane & 15, quad = lane >> 4;
    const int mBase = blockIdx.y * 128;
    const int nBase = blockIdx.x * 128;

    f32x4 acc[4][4] = {};

    const int r0 = t >> 2, kc = (t & 3) * 8;
    const u16* gA0 = A + (size_t)(mBase + r0) * K + kc;
    const u16* gA1 = A + (size_t)(mBase + 64 + r0) * K + kc;
    const u16* gB0 = Bm + (size_t)(nBase + r0) * K + kc;
    const u16* gB1 = Bm + (size_t)(nBase + 64 + r0) * K + kc;

    for (int kt = 0; kt < K; kt += 32) {
        const uint4 va0 = *(const uint4*)gA0;
        const uint4 va1 = *(const uint4*)gA1;
        const uint4 vb0 = *(const uint4*)gB0;
        const uint4 vb1 = *(const uint4*)gB1;
        gA0 += 32; gA1 += 32; gB0 += 32; gB1 += 32;
        __syncthreads();  // prior iteration's LDS reads complete
        *(uint4*)&lA[t * 8] = va0;
        *(uint4*)&lA[(t + 256) * 8] = va1;
        *(uint4*)&lB[t * 8] = vb0;
        *(uint4*)&lB[(t + 256) * 8] = vb1;
        __syncthreads();  // stores visible to all waves

        bf16x8 aF[4], bF[4];
#pragma unroll
        for (int i = 0; i < 4; ++i)
            aF[i] = ldfrag(&lA[(wrow * 64 + i * 16 + ln15) * 32 + quad * 8]);
#pragma unroll
        for (int j = 0; j < 4; ++j)
            bF[j] = ldfrag(&lB[(wcol * 64 + j * 16 + ln15) * 32 + quad * 8]);
#pragma unroll
        for (int i = 0; i < 4; ++i)
#pragma unroll
            for (int j = 0; j < 4; ++j)
                acc[i][j] = mfma16(aF[i], bF[j], acc[i][j]);
    }

    // epilogue: C[row=quad*4+r][col=ln15] per 16x16 tile (m89/m91 layout)
#pragma unroll
    for (int j = 0; j < 4; ++j) {
        const int col = nBase + wcol * 64 + j * 16 + ln15;
        const float bcol = bias[col];
#pragma unroll
        for (int i = 0; i < 4; ++i) {
#pragma unroll
            for (int r = 0; r < 4; ++r) {
                const int row = mBase + wrow * 64 + i * 16 + quad * 4 + r;
                float v = acc[i][j][r] + bcol;
                if (GELU) v = 0.5f * v * (1.0f + erff(v * 0.70710678118f));
                if (RESID) v += resid[(size_t)row * N + col];
                if (OUTF)
                    ((float*)Cv)[(size_t)row * N + col] = v;
                else
                    ((u16*)Cv)[(size_t)row * N + col] = f2bf(v);
            }
        }
    }
}

// ---------------------------------------------------------------------------
// LN1 chunk: y[r,:] = bf16( LN(x[bi,(l+SHIFT)%L,:]) * g + b ), fp32 input
// ---------------------------------------------------------------------------
__global__ __launch_bounds__(256, 4) void ln1_kernel(
    const float* __restrict__ x, const float* __restrict__ g,
    const float* __restrict__ bb, u16* __restrict__ y, int rowBase) {
    const int row = rowBase + blockIdx.x;
    const int bi = row >> 12, l = row & 4095;
    const float* src = x + ((size_t)(bi << 12) + ((l + SHIFT_) & 4095)) * 1024;
    const int t = threadIdx.x;
    const int lane = t & 63, wv = t >> 6;

    const float4 u = ((const float4*)src)[t];
    float v[4] = {u.x, u.y, u.z, u.w};
    float sum = 0.f, sq = 0.f;
#pragma unroll
    for (int k = 0; k < 4; ++k) { sum += v[k]; sq += v[k] * v[k]; }
    for (int off = 32; off > 0; off >>= 1) {
        sum += __shfl_down(sum, off);
        sq += __shfl_down(sq, off);
    }
    __shared__ float red[8];
    __shared__ float smu, srs;
    if (lane == 0) { red[wv] = sum; red[4 + wv] = sq; }
    __syncthreads();
    if (t == 0) {
        float s = red[0] + red[1] + red[2] + red[3];
        float q = red[4] + red[5] + red[6] + red[7];
        float mu = s * (1.0f / 1024.0f);
        float var = q * (1.0f / 1024.0f) - mu * mu;
        smu = mu;
        srs = rsqrtf(var + 1e-5f);
    }
    __syncthreads();
    const float mu = smu, rs = srs;
    const float4 gv = ((const float4*)g)[t];
    const float4 bv = ((const float4*)bb)[t];
    u16x4 outv;
    outv[0] = f2bf((v[0] - mu) * rs * gv.x + bv.x);
    outv[1] = f2bf((v[1] - mu) * rs * gv.y + bv.y);
    outv[2] = f2bf((v[2] - mu) * rs * gv.z + bv.z);
    outv[3] = f2bf((v[3] - mu) * rs * gv.w + bv.w);
    ((u16x4*)(y + (size_t)blockIdx.x * 1024))[t] = outv;
}

// ---------------------------------------------------------------------------
// LN2 fused (full M): x2 = x + roll(o2,+32)  (fp32, written to d_out)
//                     z  = bf16( LN(x2)*g + b )
// ---------------------------------------------------------------------------
__global__ __launch_bounds__(256, 4) void ln2_kernel(
    const float* __restrict__ x, const u16* __restrict__ o2,
    const float* __restrict__ g, const float* __restrict__ bb,
    float* __restrict__ x2, u16* __restrict__ z) {
    const int row = blockIdx.x;
    const int bi = row >> 12, l = row & 4095;
    const size_t srcO = (size_t)(bi << 12) + ((l - SHIFT_) & 4095);
    const int t = threadIdx.x;
    const int lane = t & 63, wv = t >> 6;

    const float4 ux = ((const float4*)(x + (size_t)row * 1024))[t];
    const u16x4 uo = ((const u16x4*)(o2 + srcO * 1024))[t];
    float v[4];
    v[0] = ux.x + bf2f(uo[0]);
    v[1] = ux.y + bf2f(uo[1]);
    v[2] = ux.z + bf2f(uo[2]);
    v[3] = ux.w + bf2f(uo[3]);
    float sum = 0.f, sq = 0.f;
#pragma unroll
    for (int k = 0; k < 4; ++k) { sum += v[k]; sq += v[k] * v[k]; }
    float4 x2v = {v[0], v[1], v[2], v[3]};
    ((float4*)(x2 + (size_t)row * 1024))[t] = x2v;

    for (int off = 32; off > 0; off >>= 1) {
        sum += __shfl_down(sum, off);
        sq += __shfl_down(sq, off);
    }
    __shared__ float red[8];
    __shared__ float smu, srs;
    if (lane == 0) { red[wv] = sum; red[4 + wv] = sq; }
    __syncthreads();
    if (t == 0) {
        float s = red[0] + red[1] + red[2] + red[3];
        float q = red[4] + red[5] + red[6] + red[7];
        float mu = s * (1.0f / 1024.0f);
        float var = q * (1.0f / 1024.0f) - mu * mu;
        smu = mu;
        srs = rsqrtf(var + 1e-5f);
    }
    __syncthreads();
    const float mu = smu, rs = srs;
    const float4 gv = ((const float4*)g)[t];
    const float4 bv = ((const float4*)bb)[t];
    u16x4 outv;
    outv[0] = f2bf((v[0] - mu) * rs * gv.x + bv.x);
    outv[1] = f2bf((v[1] - mu) * rs * gv.y + bv.y);
    outv[2] = f2bf((v[2] - mu) * rs * gv.z + bv.z);
    outv[3] = f2bf((v[3] - mu) * rs * gv.w + bv.w);
    ((u16x4*)(z + (size_t)row * 1024))[t] = outv;
}

// ---------------------------------------------------------------------------
// Windowed attention (chunk-local, bf16 in/out): block = (window, head).
// ---------------------------------------------------------------------------
__global__ __launch_bounds__(256, 2) void attn_kernel(
    const u16* __restrict__ qkv, u16* __restrict__ o) {
    __shared__ __align__(16) u16 sQ[64 * 64];  // reused as P
    __shared__ __align__(16) u16 sK[64 * 64];
    __shared__ __align__(16) u16 sV[64 * 64];
    __shared__ float sS[64 * 66];

    const int t = threadIdx.x;
    const int win = blockIdx.x >> 4;
    const int head = blockIdx.x & 15;
    const size_t rowbase = (size_t)win * 64;
    const u16* base = qkv + rowbase * 3072 + head * 64;

    {  // stage Q,K,V: chunks c = t, t+256 : row=c>>3, dcol=(c&7)*8
        const int c0 = t, c1 = t + 256;
        const int r0 = c0 >> 3, d0 = (c0 & 7) * 8;
        const int r1 = c1 >> 3, d1 = (c1 & 7) * 8;
        const u16* g0 = base + (size_t)r0 * 3072 + d0;
        const u16* g1 = base + (size_t)r1 * 3072 + d1;
        const uint4 q0 = *(const uint4*)g0;
        const uint4 q1 = *(const uint4*)g1;
        const uint4 k0 = *(const uint4*)(g0 + 1024);
        const uint4 k1 = *(const uint4*)(g1 + 1024);
        const uint4 v0 = *(const uint4*)(g0 + 2048);
        const uint4 v1 = *(const uint4*)(g1 + 2048);
        *(uint4*)&sQ[c0 * 8] = q0;
        *(uint4*)&sQ[c1 * 8] = q1;
        *(uint4*)&sK[c0 * 8] = k0;
        *(uint4*)&sK[c1 * 8] = k1;
        *(uint4*)&sV[c0 * 8] = v0;
        *(uint4*)&sV[c1 * 8] = v1;
    }
    __syncthreads();

    const int lane = t & 63, wv = t >> 6;
    const int ln15 = lane & 15, quad = lane >> 4;

    // S = Q K^T * scale : wave wv -> rows [16wv,16wv+16), all 64 cols
    f32x4 accS[4] = {};
#pragma unroll
    for (int kb = 0; kb < 2; ++kb) {
        bf16x8 aF = ldfrag(&sQ[(wv * 16 + ln15) * 64 + kb * 32 + quad * 8]);
#pragma unroll
        for (int jt = 0; jt < 4; ++jt) {
            bf16x8 bF = ldfrag(&sK[(jt * 16 + ln15) * 64 + kb * 32 + quad * 8]);
            accS[jt] = mfma16(aF, bF, accS[jt]);
        }
    }
#pragma unroll
    for (int jt = 0; jt < 4; ++jt)
#pragma unroll
        for (int r = 0; r < 4; ++r)
            sS[(wv * 16 + quad * 4 + r) * 66 + jt * 16 + ln15] =
                accS[jt][r] * 0.125f;
    __syncthreads();

    // softmax: 4 threads per row, 16 cols each; P -> sQ (bf16)
    {
        const int row = t >> 2, part = t & 3;
        const float* sr = &sS[row * 66 + part * 16];
        float vals[16];
        float mx = -1e30f;
#pragma unroll
        for (int i = 0; i < 16; ++i) {
            vals[i] = sr[i];
            mx = fmaxf(mx, vals[i]);
        }
        mx = fmaxf(mx, __shfl_xor(mx, 1));
        mx = fmaxf(mx, __shfl_xor(mx, 2));
        float sum = 0.f;
#pragma unroll
        for (int i = 0; i < 16; ++i) {
            vals[i] = __expf(vals[i] - mx);
            sum += vals[i];
        }
        sum += __shfl_xor(sum, 1);
        sum += __shfl_xor(sum, 2);
        const float inv = 1.0f / sum;
        u16* pr = &sQ[row * 64 + part * 16];
#pragma unroll
        for (int i = 0; i < 16; ++i) pr[i] = f2bf(vals[i] * inv);
    }
    __syncthreads();

    // O = P V : wave wv -> rows [16wv,16wv+16), all 64 d-cols
    f32x4 accO[4] = {};
#pragma unroll
    for (int kb = 0; kb < 2; ++kb) {
        bf16x8 aF = ldfrag(&sQ[(wv * 16 + ln15) * 64 + kb * 32 + quad * 8]);
#pragma unroll
        for (int dt = 0; dt < 4; ++dt) {
            u16 tmp[8];
#pragma unroll
            for (int j = 0; j < 8; ++j)
                tmp[j] = sV[(kb * 32 + quad * 8 + j) * 64 + dt * 16 + ln15];
            bf16x8 bF;
            __builtin_memcpy(&bF, tmp, 16);
            accO[dt] = mfma16(aF, bF, accO[dt]);
        }
    }
    u16* ob = o + rowbase * 1024 + head * 64;
#pragma unroll
    for (int dt = 0; dt < 4; ++dt)
#pragma unroll
        for (int r = 0; r < 4; ++r) {
            const int q = wv * 16 + quad * 4 + r;
            const int d = dt * 16 + ln15;
            ob[(size_t)q * 1024 + d] = f2bf(accO[dt][r]);
        }
}

// ---------------------------------------------------------------------------
extern "C" void kernel_launch(void* const* d_in, const int* in_sizes, int n_in,
                              void* d_out, int out_size, void* d_ws,
                              size_t ws_size, hipStream_t stream) {
    (void)in_sizes; (void)n_in; (void)out_size; (void)ws_size;
    // ALL inputs are fp32 per reference setup_inputs(); output fp32.
    const float* x = (const float*)d_in[0];
    const float* ln1_g = (const float*)d_in[1];
    const float* ln1_b = (const float*)d_in[2];
    const float* in_proj_w = (const float*)d_in[3];
    const float* in_proj_b = (const float*)d_in[4];
    const float* out_proj_w = (const float*)d_in[5];
    const float* out_proj_b = (const float*)d_in[6];
    const float* ln2_g = (const float*)d_in[7];
    const float* ln2_b = (const float*)d_in[8];
    const float* w1 = (const float*)d_in[9];
    const float* b1 = (const float*)d_in[10];
    const float* w2 = (const float*)d_in[11];
    const float* b2 = (const float*)d_in[12];
    float* out = (float*)d_out;

    // Workspace (108 MB):
    //   [  0,  6M) in_proj_w bf16      [  6,  8M) out_proj_w bf16
    //   [  8, 16M) w1 bf16             [ 16, 24M) w2 bf16
    //   [ 24, 56M) o2 bf16 (full M)    [ 56, 88M) z bf16 (full M)
    //   [ 88,108M) chunk region: phase A qin_c(4)+qkv_c(12)+o_c(4);
    //              phase C h_c(16)
    // x2 (fp32, full M) lives in d_out; FF2 reads it as resid and overwrites.
    char* ws = (char*)d_ws;
    const size_t MB = 1024 * 1024;
    u16* wb_inproj = (u16*)(ws + 0 * MB);
    u16* wb_outproj = (u16*)(ws + 6 * MB);
    u16* wb_w1 = (u16*)(ws + 8 * MB);
    u16* wb_w2 = (u16*)(ws + 16 * MB);
    u16* o2 = (u16*)(ws + 24 * MB);
    u16* z = (u16*)(ws + 56 * MB);
    u16* qin_c = (u16*)(ws + 88 * MB);
    u16* qkv_c = (u16*)(ws + 92 * MB);
    u16* o_c = (u16*)(ws + 104 * MB);
    u16* h_c = (u16*)(ws + 88 * MB);
    float* x2 = out;

    const int M = B_ * L_;    // 16384
    const int NCH = M / MC_;  // 8

    // Prologue: convert weights fp32 -> bf16
    cvt_kernel<<<(3 * H_ * H_ / 4 + 255) / 256, 256, 0, stream>>>(
        in_proj_w, wb_inproj, 3 * H_ * H_ / 4);
    cvt_kernel<<<(H_ * H_ / 4 + 255) / 256, 256, 0, stream>>>(
        out_proj_w, wb_outproj, H_ * H_ / 4);
    cvt_kernel<<<(FF_ * H_ / 4 + 255) / 256, 256, 0, stream>>>(
        w1, wb_w1, FF_ * H_ / 4);
    cvt_kernel<<<(H_ * FF_ / 4 + 255) / 256, 256, 0, stream>>>(
        w2, wb_w2, H_ * FF_ / 4);

    // Phase A: ln1 -> qkv proj -> windowed attn -> out_proj, per chunk
    for (int c = 0; c < NCH; ++c) {
        const int rowBase = c * MC_;
        ln1_kernel<<<MC_, 256, 0, stream>>>(x, ln1_g, ln1_b, qin_c, rowBase);
        gemm_bt<0, 0, 0><<<dim3(3 * H_ / 128, MC_ / 128), 256, 0, stream>>>(
            qin_c, wb_inproj, in_proj_b, nullptr, qkv_c, MC_, 3 * H_, H_);
        attn_kernel<<<(MC_ / W_) * NH_, 256, 0, stream>>>(qkv_c, o_c);
        gemm_bt<0, 0, 0><<<dim3(H_ / 128, MC_ / 128), 256, 0, stream>>>(
            o_c, wb_outproj, out_proj_b, nullptr,
            o2 + (size_t)rowBase * H_, MC_, H_, H_);
    }

    // Phase B: x2 = x + roll(o2,+32) (fp32 -> d_out), z = bf16(LN2(x2))
    ln2_kernel<<<M, 256, 0, stream>>>(x, o2, ln2_g, ln2_b, x2, z);

    // Phase C: FFN per chunk; FF2 reads resid x2 rows from d_out and
    // overwrites the same rows with the final output (same-thread RMW).
    for (int c = 0; c < NCH; ++c) {
        const size_t off = (size_t)c * MC_ * H_;
        gemm_bt<1, 0, 0><<<dim3(FF_ / 128, MC_ / 128), 256, 0, stream>>>(
            z + off, wb_w1, b1, nullptr, h_c, MC_, FF_, H_);
        gemm_bt<0, 1, 1><<<dim3(H_ / 128, MC_ / 128), 256, 0, stream>>>(
            h_c, wb_w2, b2, x2 + off, out + off, MC_, H_, FF_);
    }
}

// Round 4
// 913.073 us; speedup vs baseline: 1.7262x; 1.7262x over previous
//
#include <hip/hip_runtime.h>
#include <cstdint>
#include <cstddef>

#define B_ 4
#define L_ 4096
#define H_ 1024
#define NH_ 16
#define W_ 64
#define SHIFT_ 32
#define FF_ 4096
#define HD_ 64
#define MCA_ 8192  // phase-A chunk rows (2 chunks)

typedef unsigned short u16;
typedef __attribute__((ext_vector_type(8))) __bf16 bf16x8;
typedef __attribute__((ext_vector_type(4))) float f32x4;
typedef __attribute__((ext_vector_type(4))) unsigned short u16x4;

__device__ __forceinline__ float bf2f(u16 u) {
    unsigned int x = ((unsigned int)u) << 16;
    float f;
    __builtin_memcpy(&f, &x, 4);
    return f;
}
__device__ __forceinline__ u16 f2bf(float f) {
    unsigned int u;
    __builtin_memcpy(&u, &f, 4);
    u = (u + 0x7fffu + ((u >> 16) & 1u)) >> 16;  // RNE
    return (u16)u;
}

__device__ __forceinline__ void gload16(const u16* g, u16* l) {
    __builtin_amdgcn_global_load_lds(
        (const __attribute__((address_space(1))) void*)g,
        (__attribute__((address_space(3))) void*)l, 16, 0, 0);
}

__device__ __forceinline__ bf16x8 ldfrag(const u16* p) {
    uint4 v = *(const uint4*)p;  // ds_read_b128
    bf16x8 r;
    __builtin_memcpy(&r, &v, 16);
    return r;
}

__device__ __forceinline__ f32x4 mfma16(bf16x8 a, bf16x8 b, f32x4 c) {
    return __builtin_amdgcn_mfma_f32_16x16x32_bf16(a, b, c, 0, 0, 0);
}

// ---------------------------------------------------------------------------
// fp32 -> bf16 conversion (weights prologue)
// ---------------------------------------------------------------------------
__global__ __launch_bounds__(256) void cvt_kernel(
    const float* __restrict__ src, u16* __restrict__ dst, int n4) {
    const int i = blockIdx.x * 256 + threadIdx.x;
    if (i < n4) {
        const float4 v = ((const float4*)src)[i];
        u16x4 o;
        o[0] = f2bf(v.x); o[1] = f2bf(v.y);
        o[2] = f2bf(v.z); o[3] = f2bf(v.w);
        ((u16x4*)dst)[i] = o;
    }
}

// ---------------------------------------------------------------------------
// GEMM: C[M,N] = act(A[M,K]bf16 @ B[N,K(ldb)]bf16^T [+bias] ) [+resid f32]
// 128x128 tile, BK=32, 256 threads (4 waves 2x2), global_load_lds width=16
// staging (m97 structure). OUTF: 0 = bf16 out, 1 = fp32 out.
// ---------------------------------------------------------------------------
template <int GELU, int RESID, int BIAS, int OUTF>
__global__ __launch_bounds__(256, 2) void gemm_bt(
    const u16* __restrict__ A, const u16* __restrict__ Bm, int ldb,
    const float* __restrict__ bias, const float* __restrict__ resid,
    void* __restrict__ Cv, int M, int N, int K) {
    __shared__ __align__(16) u16 lA[128 * 32];
    __shared__ __align__(16) u16 lB[128 * 32];

    const int t = threadIdx.x;
    const int lane = t & 63;
    const int wv = t >> 6;
    const int wrow = wv >> 1, wcol = wv & 1;
    const int ln15 = lane & 15, quad = lane >> 4;
    const int mBase = blockIdx.y * 128;
    const int nBase = blockIdx.x * 128;

    f32x4 acc[4][4] = {};

    // staging: chunk c covers (row=c>>2, kchunk=(c&3)*8); c = t and t+256
    const int r0 = t >> 2, kc = (t & 3) * 8;
    const u16* gA0 = A + (size_t)(mBase + r0) * K + kc;
    const u16* gA1 = A + (size_t)(mBase + 64 + r0) * K + kc;
    const u16* gB0 = Bm + (size_t)(nBase + r0) * ldb + kc;
    const u16* gB1 = Bm + (size_t)(nBase + 64 + r0) * ldb + kc;
    u16* lA0 = &lA[t * 8];
    u16* lA1 = &lA[(t + 256) * 8];
    u16* lB0 = &lB[t * 8];
    u16* lB1 = &lB[(t + 256) * 8];

    for (int kt = 0; kt < K; kt += 32) {
        gload16(gA0, lA0);
        gload16(gA1, lA1);
        gload16(gB0, lB0);
        gload16(gB1, lB1);
        gA0 += 32; gA1 += 32; gB0 += 32; gB1 += 32;
        __syncthreads();  // drain DMA (vmcnt(0) at barrier)

        bf16x8 aF[4], bF[4];
#pragma unroll
        for (int i = 0; i < 4; ++i)
            aF[i] = ldfrag(&lA[(wrow * 64 + i * 16 + ln15) * 32 + quad * 8]);
#pragma unroll
        for (int j = 0; j < 4; ++j)
            bF[j] = ldfrag(&lB[(wcol * 64 + j * 16 + ln15) * 32 + quad * 8]);
#pragma unroll
        for (int i = 0; i < 4; ++i)
#pragma unroll
            for (int j = 0; j < 4; ++j)
                acc[i][j] = mfma16(aF[i], bF[j], acc[i][j]);
        __syncthreads();  // all reads done before next iter's DMA writes
    }

    // epilogue: C[row=quad*4+r][col=ln15] per 16x16 tile (m89/m91 layout)
#pragma unroll
    for (int j = 0; j < 4; ++j) {
        const int col = nBase + wcol * 64 + j * 16 + ln15;
        const float bcol = BIAS ? bias[col] : 0.0f;
#pragma unroll
        for (int i = 0; i < 4; ++i) {
#pragma unroll
            for (int r = 0; r < 4; ++r) {
                const int row = mBase + wrow * 64 + i * 16 + quad * 4 + r;
                float v = acc[i][j][r] + bcol;
                if (GELU) v = 0.5f * v * (1.0f + erff(v * 0.70710678118f));
                if (RESID) v += resid[(size_t)row * N + col];
                if (OUTF)
                    ((float*)Cv)[(size_t)row * N + col] = v;
                else
                    ((u16*)Cv)[(size_t)row * N + col] = f2bf(v);
            }
        }
    }
}

// ---------------------------------------------------------------------------
// LN1 chunk: y[r,:] = bf16( LN(x[bi,(l+SHIFT)%L,:]) * g + b ), fp32 input
// ---------------------------------------------------------------------------
__global__ __launch_bounds__(256, 4) void ln1_kernel(
    const float* __restrict__ x, const float* __restrict__ g,
    const float* __restrict__ bb, u16* __restrict__ y, int rowBase) {
    const int row = rowBase + blockIdx.x;
    const int bi = row >> 12, l = row & 4095;
    const float* src = x + ((size_t)(bi << 12) + ((l + SHIFT_) & 4095)) * 1024;
    const int t = threadIdx.x;
    const int lane = t & 63, wv = t >> 6;

    const float4 u = ((const float4*)src)[t];
    float v[4] = {u.x, u.y, u.z, u.w};
    float sum = 0.f, sq = 0.f;
#pragma unroll
    for (int k = 0; k < 4; ++k) { sum += v[k]; sq += v[k] * v[k]; }
    for (int off = 32; off > 0; off >>= 1) {
        sum += __shfl_down(sum, off);
        sq += __shfl_down(sq, off);
    }
    __shared__ float red[8];
    __shared__ float smu, srs;
    if (lane == 0) { red[wv] = sum; red[4 + wv] = sq; }
    __syncthreads();
    if (t == 0) {
        float s = red[0] + red[1] + red[2] + red[3];
        float q = red[4] + red[5] + red[6] + red[7];
        float mu = s * (1.0f / 1024.0f);
        float var = q * (1.0f / 1024.0f) - mu * mu;
        smu = mu;
        srs = rsqrtf(var + 1e-5f);
    }
    __syncthreads();
    const float mu = smu, rs = srs;
    const float4 gv = ((const float4*)g)[t];
    const float4 bv = ((const float4*)bb)[t];
    u16x4 outv;
    outv[0] = f2bf((v[0] - mu) * rs * gv.x + bv.x);
    outv[1] = f2bf((v[1] - mu) * rs * gv.y + bv.y);
    outv[2] = f2bf((v[2] - mu) * rs * gv.z + bv.z);
    outv[3] = f2bf((v[3] - mu) * rs * gv.w + bv.w);
    ((u16x4*)(y + (size_t)blockIdx.x * 1024))[t] = outv;
}

// ---------------------------------------------------------------------------
// LN2 fused (full M): x2 = x + roll(o2,+32)  (fp32 -> d_out)
//                     z  = bf16( LN(x2)*g + b )
// ---------------------------------------------------------------------------
__global__ __launch_bounds__(256, 4) void ln2_kernel(
    const float* __restrict__ x, const u16* __restrict__ o2,
    const float* __restrict__ g, const float* __restrict__ bb,
    float* __restrict__ x2, u16* __restrict__ z) {
    const int row = blockIdx.x;
    const int bi = row >> 12, l = row & 4095;
    const size_t srcO = (size_t)(bi << 12) + ((l - SHIFT_) & 4095);
    const int t = threadIdx.x;
    const int lane = t & 63, wv = t >> 6;

    const float4 ux = ((const float4*)(x + (size_t)row * 1024))[t];
    const u16x4 uo = ((const u16x4*)(o2 + srcO * 1024))[t];
    float v[4];
    v[0] = ux.x + bf2f(uo[0]);
    v[1] = ux.y + bf2f(uo[1]);
    v[2] = ux.z + bf2f(uo[2]);
    v[3] = ux.w + bf2f(uo[3]);
    float sum = 0.f, sq = 0.f;
#pragma unroll
    for (int k = 0; k < 4; ++k) { sum += v[k]; sq += v[k] * v[k]; }
    float4 x2v = {v[0], v[1], v[2], v[3]};
    ((float4*)(x2 + (size_t)row * 1024))[t] = x2v;

    for (int off = 32; off > 0; off >>= 1) {
        sum += __shfl_down(sum, off);
        sq += __shfl_down(sq, off);
    }
    __shared__ float red[8];
    __shared__ float smu, srs;
    if (lane == 0) { red[wv] = sum; red[4 + wv] = sq; }
    __syncthreads();
    if (t == 0) {
        float s = red[0] + red[1] + red[2] + red[3];
        float q = red[4] + red[5] + red[6] + red[7];
        float mu = s * (1.0f / 1024.0f);
        float var = q * (1.0f / 1024.0f) - mu * mu;
        smu = mu;
        srs = rsqrtf(var + 1e-5f);
    }
    __syncthreads();
    const float mu = smu, rs = srs;
    const float4 gv = ((const float4*)g)[t];
    const float4 bv = ((const float4*)bb)[t];
    u16x4 outv;
    outv[0] = f2bf((v[0] - mu) * rs * gv.x + bv.x);
    outv[1] = f2bf((v[1] - mu) * rs * gv.y + bv.y);
    outv[2] = f2bf((v[2] - mu) * rs * gv.z + bv.z);
    outv[3] = f2bf((v[3] - mu) * rs * gv.w + bv.w);
    ((u16x4*)(z + (size_t)row * 1024))[t] = outv;
}

// ---------------------------------------------------------------------------
// Windowed attention (chunk-local, bf16 in/out): block = (window, head).
// ---------------------------------------------------------------------------
__global__ __launch_bounds__(256, 2) void attn_kernel(
    const u16* __restrict__ qkv, u16* __restrict__ o) {
    __shared__ __align__(16) u16 sQ[64 * 64];  // reused as P
    __shared__ __align__(16) u16 sK[64 * 64];
    __shared__ __align__(16) u16 sV[64 * 64];
    __shared__ float sS[64 * 66];

    const int t = threadIdx.x;
    const int win = blockIdx.x >> 4;
    const int head = blockIdx.x & 15;
    const size_t rowbase = (size_t)win * 64;
    const u16* base = qkv + rowbase * 3072 + head * 64;

    {  // stage Q,K,V via global_load_lds: chunks c = t, t+256
        const int c0 = t, c1 = t + 256;
        const int r0 = c0 >> 3, d0 = (c0 & 7) * 8;
        const int r1 = c1 >> 3, d1 = (c1 & 7) * 8;
        const u16* g0 = base + (size_t)r0 * 3072 + d0;
        const u16* g1 = base + (size_t)r1 * 3072 + d1;
        gload16(g0, &sQ[c0 * 8]);
        gload16(g1, &sQ[c1 * 8]);
        gload16(g0 + 1024, &sK[c0 * 8]);
        gload16(g1 + 1024, &sK[c1 * 8]);
        gload16(g0 + 2048, &sV[c0 * 8]);
        gload16(g1 + 2048, &sV[c1 * 8]);
    }
    __syncthreads();

    const int lane = t & 63, wv = t >> 6;
    const int ln15 = lane & 15, quad = lane >> 4;

    // S = Q K^T * scale : wave wv -> rows [16wv,16wv+16), all 64 cols
    f32x4 accS[4] = {};
#pragma unroll
    for (int kb = 0; kb < 2; ++kb) {
        bf16x8 aF = ldfrag(&sQ[(wv * 16 + ln15) * 64 + kb * 32 + quad * 8]);
#pragma unroll
        for (int jt = 0; jt < 4; ++jt) {
            bf16x8 bF = ldfrag(&sK[(jt * 16 + ln15) * 64 + kb * 32 + quad * 8]);
            accS[jt] = mfma16(aF, bF, accS[jt]);
        }
    }
#pragma unroll
    for (int jt = 0; jt < 4; ++jt)
#pragma unroll
        for (int r = 0; r < 4; ++r)
            sS[(wv * 16 + quad * 4 + r) * 66 + jt * 16 + ln15] =
                accS[jt][r] * 0.125f;
    __syncthreads();

    // softmax: 4 threads per row, 16 cols each; P -> sQ (bf16)
    {
        const int row = t >> 2, part = t & 3;
        const float* sr = &sS[row * 66 + part * 16];
        float vals[16];
        float mx = -1e30f;
#pragma unroll
        for (int i = 0; i < 16; ++i) {
            vals[i] = sr[i];
            mx = fmaxf(mx, vals[i]);
        }
        mx = fmaxf(mx, __shfl_xor(mx, 1));
        mx = fmaxf(mx, __shfl_xor(mx, 2));
        float sum = 0.f;
#pragma unroll
        for (int i = 0; i < 16; ++i) {
            vals[i] = __expf(vals[i] - mx);
            sum += vals[i];
        }
        sum += __shfl_xor(sum, 1);
        sum += __shfl_xor(sum, 2);
        const float inv = 1.0f / sum;
        u16* pr = &sQ[row * 64 + part * 16];
#pragma unroll
        for (int i = 0; i < 16; ++i) pr[i] = f2bf(vals[i] * inv);
    }
    __syncthreads();

    // O = P V : wave wv -> rows [16wv,16wv+16), all 64 d-cols
    f32x4 accO[4] = {};
#pragma unroll
    for (int kb = 0; kb < 2; ++kb) {
        bf16x8 aF = ldfrag(&sQ[(wv * 16 + ln15) * 64 + kb * 32 + quad * 8]);
#pragma unroll
        for (int dt = 0; dt < 4; ++dt) {
            u16 tmp[8];
#pragma unroll
            for (int j = 0; j < 8; ++j)
                tmp[j] = sV[(kb * 32 + quad * 8 + j) * 64 + dt * 16 + ln15];
            bf16x8 bF;
            __builtin_memcpy(&bF, tmp, 16);
            accO[dt] = mfma16(aF, bF, accO[dt]);
        }
    }
    u16* ob = o + rowbase * 1024 + head * 64;
#pragma unroll
    for (int dt = 0; dt < 4; ++dt)
#pragma unroll
        for (int r = 0; r < 4; ++r) {
            const int q = wv * 16 + quad * 4 + r;
            const int d = dt * 16 + ln15;
            ob[(size_t)q * 1024 + d] = f2bf(accO[dt][r]);
        }
}

// ---------------------------------------------------------------------------
extern "C" void kernel_launch(void* const* d_in, const int* in_sizes, int n_in,
                              void* d_out, int out_size, void* d_ws,
                              size_t ws_size, hipStream_t stream) {
    (void)in_sizes; (void)n_in; (void)out_size; (void)ws_size;
    const float* x = (const float*)d_in[0];
    const float* ln1_g = (const float*)d_in[1];
    const float* ln1_b = (const float*)d_in[2];
    const float* in_proj_w = (const float*)d_in[3];
    const float* in_proj_b = (const float*)d_in[4];
    const float* out_proj_w = (const float*)d_in[5];
    const float* out_proj_b = (const float*)d_in[6];
    const float* ln2_g = (const float*)d_in[7];
    const float* ln2_b = (const float*)d_in[8];
    const float* w1 = (const float*)d_in[9];
    const float* b1 = (const float*)d_in[10];
    const float* w2 = (const float*)d_in[11];
    const float* b2 = (const float*)d_in[12];
    float* out = (float*)d_out;

    // Workspace (104 MB high-water):
    //   [  0,  8M) w1 bf16 (persist)     [  8, 16M) w2 bf16 (persist)
    //   [ 16, 22M) in_proj bf16 (A)      [ 22, 24M) out_proj bf16 (A)
    //   [ 24, 72M) qkv_c bf16 (A, 8192 rows x 3072)
    //   [ 72,104M) o2 bf16 full M (A/B)
    //   [ 16, 48M) z bf16 full M (B/C — overlays in/out_proj + qkv head)
    //   [ 48, 80M) h_buf bf16 (C, full M x 1024 col-split)
    // d_out doubles as scratch: phase A qin [0,16M) + o_full [16,48M);
    // phase B/C x2 fp32 (all 64 MB), finally overwritten by FF2 passes.
    char* ws = (char*)d_ws;
    const size_t MB = 1024 * 1024;
    u16* wb_w1 = (u16*)(ws + 0 * MB);
    u16* wb_w2 = (u16*)(ws + 8 * MB);
    u16* wb_inproj = (u16*)(ws + 16 * MB);
    u16* wb_outproj = (u16*)(ws + 22 * MB);
    u16* qkv_c = (u16*)(ws + 24 * MB);
    u16* o2 = (u16*)(ws + 72 * MB);
    u16* z = (u16*)(ws + 16 * MB);
    u16* h_buf = (u16*)(ws + 48 * MB);

    u16* qin = (u16*)d_out;                          // [0,16M) of d_out
    u16* o_full = (u16*)((char*)d_out + 16 * MB);    // [16,48M) of d_out
    float* x2 = out;

    const int M = B_ * L_;  // 16384

    // Prologue: weights fp32 -> bf16
    cvt_kernel<<<(FF_ * H_ / 4 + 255) / 256, 256, 0, stream>>>(
        w1, wb_w1, FF_ * H_ / 4);
    cvt_kernel<<<(H_ * FF_ / 4 + 255) / 256, 256, 0, stream>>>(
        w2, wb_w2, H_ * FF_ / 4);
    cvt_kernel<<<(3 * H_ * H_ / 4 + 255) / 256, 256, 0, stream>>>(
        in_proj_w, wb_inproj, 3 * H_ * H_ / 4);
    cvt_kernel<<<(H_ * H_ / 4 + 255) / 256, 256, 0, stream>>>(
        out_proj_w, wb_outproj, H_ * H_ / 4);

    // Phase A: ln1 -> qkv proj -> windowed attn (2 chunks of 8192 rows)
    for (int c = 0; c < 2; ++c) {
        const int rowBase = c * MCA_;
        ln1_kernel<<<MCA_, 256, 0, stream>>>(x, ln1_g, ln1_b, qin, rowBase);
        gemm_bt<0, 0, 1, 0>
            <<<dim3(3 * H_ / 128, MCA_ / 128), 256, 0, stream>>>(
                qin, wb_inproj, H_, in_proj_b, nullptr, qkv_c,
                MCA_, 3 * H_, H_);
        attn_kernel<<<(MCA_ / W_) * NH_, 256, 0, stream>>>(
            qkv_c, o_full + (size_t)rowBase * H_);
    }
    // out_proj over full M (1024 blocks)
    gemm_bt<0, 0, 1, 0><<<dim3(H_ / 128, M / 128), 256, 0, stream>>>(
        o_full, wb_outproj, H_, out_proj_b, nullptr, o2, M, H_, H_);

    // Phase B: x2 = x + roll(o2,+32) (fp32 -> d_out), z = bf16(LN2(x2))
    ln2_kernel<<<M, 256, 0, stream>>>(x, o2, ln2_g, ln2_b, x2, z);

    // Phase C: FFN as 4 column-splits of FF (all dispatches 1024 blocks).
    // FF1_q: h = gelu(z @ w1[q*1024:(q+1)*1024]^T + b1_q)      (full M)
    // FF2_q: out (+)= h @ w2[:, q*1024:(q+1)*1024]^T [+ b2 + x2 on q=0]
    for (int q = 0; q < 4; ++q) {
        gemm_bt<1, 0, 1, 0><<<dim3(H_ / 128, M / 128), 256, 0, stream>>>(
            z, wb_w1 + (size_t)q * 1024 * H_, H_, b1 + q * 1024, nullptr,
            h_buf, M, 1024, H_);
        if (q == 0)
            gemm_bt<0, 1, 1, 1><<<dim3(H_ / 128, M / 128), 256, 0, stream>>>(
                h_buf, wb_w2 + (size_t)q * 1024, FF_, b2, x2, out,
                M, H_, 1024);
        else
            gemm_bt<0, 1, 0, 1><<<dim3(H_ / 128, M / 128), 256, 0, stream>>>(
                h_buf, wb_w2 + (size_t)q * 1024, FF_, nullptr, x2, out,
                M, H_, 1024);
    }
}

// Round 5
// 843.497 us; speedup vs baseline: 1.8686x; 1.0825x over previous
//
#include <hip/hip_runtime.h>
#include <cstdint>
#include <cstddef>

#define B_ 4
#define L_ 4096
#define H_ 1024
#define NH_ 16
#define W_ 64
#define SHIFT_ 32
#define FF_ 4096
#define HD_ 64
#define MCA_ 8192  // phase-A chunk rows (2 chunks)
#define MCF_ 8192  // FFN chunk rows (2 chunks)

typedef unsigned short u16;
typedef __attribute__((ext_vector_type(8))) __bf16 bf16x8;
typedef __attribute__((ext_vector_type(4))) float f32x4;
typedef __attribute__((ext_vector_type(4))) unsigned short u16x4;

__device__ __forceinline__ float bf2f(u16 u) {
    unsigned int x = ((unsigned int)u) << 16;
    float f;
    __builtin_memcpy(&f, &x, 4);
    return f;
}
__device__ __forceinline__ u16 f2bf(float f) {
    unsigned int u;
    __builtin_memcpy(&u, &f, 4);
    u = (u + 0x7fffu + ((u >> 16) & 1u)) >> 16;  // RNE
    return (u16)u;
}

__device__ __forceinline__ void gload16(const u16* g, u16* l) {
    __builtin_amdgcn_global_load_lds(
        (const __attribute__((address_space(1))) void*)g,
        (__attribute__((address_space(3))) void*)l, 16, 0, 0);
}

__device__ __forceinline__ bf16x8 ldfrag(const u16* p) {
    uint4 v = *(const uint4*)p;  // ds_read_b128
    bf16x8 r;
    __builtin_memcpy(&r, &v, 16);
    return r;
}

__device__ __forceinline__ f32x4 mfma16(bf16x8 a, bf16x8 b, f32x4 c) {
    return __builtin_amdgcn_mfma_f32_16x16x32_bf16(a, b, c, 0, 0, 0);
}

// ---------------------------------------------------------------------------
// fp32 -> bf16 conversion (weights prologue)
// ---------------------------------------------------------------------------
__global__ __launch_bounds__(256) void cvt_kernel(
    const float* __restrict__ src, u16* __restrict__ dst, int n4) {
    const int i = blockIdx.x * 256 + threadIdx.x;
    if (i < n4) {
        const float4 v = ((const float4*)src)[i];
        u16x4 o;
        o[0] = f2bf(v.x); o[1] = f2bf(v.y);
        o[2] = f2bf(v.z); o[3] = f2bf(v.w);
        ((u16x4*)dst)[i] = o;
    }
}

// ---------------------------------------------------------------------------
// GEMM: C[M,N]bf16 = act(A[M,K]bf16 @ B[N,K(ldb)]bf16^T [+bias f32])
// 128x128 tile, BK=32, 256 threads (4 waves 2x2), global_load_lds width=16.
// ---------------------------------------------------------------------------
template <int GELU, int BIAS>
__global__ __launch_bounds__(256, 2) void gemm_bt(
    const u16* __restrict__ A, const u16* __restrict__ Bm, int ldb,
    const float* __restrict__ bias, u16* __restrict__ C,
    int M, int N, int K) {
    __shared__ __align__(16) u16 lA[128 * 32];
    __shared__ __align__(16) u16 lB[128 * 32];

    const int t = threadIdx.x;
    const int lane = t & 63;
    const int wv = t >> 6;
    const int wrow = wv >> 1, wcol = wv & 1;
    const int ln15 = lane & 15, quad = lane >> 4;
    const int mBase = blockIdx.y * 128;
    const int nBase = blockIdx.x * 128;

    f32x4 acc[4][4] = {};

    const int r0 = t >> 2, kc = (t & 3) * 8;
    const u16* gA0 = A + (size_t)(mBase + r0) * K + kc;
    const u16* gA1 = A + (size_t)(mBase + 64 + r0) * K + kc;
    const u16* gB0 = Bm + (size_t)(nBase + r0) * ldb + kc;
    const u16* gB1 = Bm + (size_t)(nBase + 64 + r0) * ldb + kc;
    u16* lA0 = &lA[t * 8];
    u16* lA1 = &lA[(t + 256) * 8];
    u16* lB0 = &lB[t * 8];
    u16* lB1 = &lB[(t + 256) * 8];

    for (int kt = 0; kt < K; kt += 32) {
        gload16(gA0, lA0);
        gload16(gA1, lA1);
        gload16(gB0, lB0);
        gload16(gB1, lB1);
        gA0 += 32; gA1 += 32; gB0 += 32; gB1 += 32;
        __syncthreads();  // drain DMA (vmcnt(0) at barrier)

        bf16x8 aF[4], bF[4];
#pragma unroll
        for (int i = 0; i < 4; ++i)
            aF[i] = ldfrag(&lA[(wrow * 64 + i * 16 + ln15) * 32 + quad * 8]);
#pragma unroll
        for (int j = 0; j < 4; ++j)
            bF[j] = ldfrag(&lB[(wcol * 64 + j * 16 + ln15) * 32 + quad * 8]);
#pragma unroll
        for (int i = 0; i < 4; ++i)
#pragma unroll
            for (int j = 0; j < 4; ++j)
                acc[i][j] = mfma16(aF[i], bF[j], acc[i][j]);
        __syncthreads();  // all reads done before next iter's DMA
    }

    // epilogue: C[row=quad*4+r][col=ln15] per 16x16 tile
#pragma unroll
    for (int j = 0; j < 4; ++j) {
        const int col = nBase + wcol * 64 + j * 16 + ln15;
        const float bcol = BIAS ? bias[col] : 0.0f;
#pragma unroll
        for (int i = 0; i < 4; ++i) {
#pragma unroll
            for (int r = 0; r < 4; ++r) {
                const int row = mBase + wrow * 64 + i * 16 + quad * 4 + r;
                float v = acc[i][j][r] + bcol;
                if (GELU) v = 0.5f * v * (1.0f + erff(v * 0.70710678118f));
                C[(size_t)row * N + col] = f2bf(v);
            }
        }
    }
}

// ---------------------------------------------------------------------------
// Final add: out[R,:] = x2[R,:] + bf2f(ff[r,:]) + b2[:]   (fully coalesced)
// ---------------------------------------------------------------------------
__global__ __launch_bounds__(256, 4) void add_kernel(
    const u16* __restrict__ ff, const float* __restrict__ b2,
    float* __restrict__ out, int rowBase) {
    const int r = blockIdx.x;
    const size_t gOff = (size_t)(rowBase + r) * 1024;
    const int t = threadIdx.x;
    const float4 xv = ((const float4*)(out + gOff))[t];
    const u16x4 fv = ((const u16x4*)(ff + (size_t)r * 1024))[t];
    const float4 bv = ((const float4*)b2)[t];
    float4 o;
    o.x = xv.x + bf2f(fv[0]) + bv.x;
    o.y = xv.y + bf2f(fv[1]) + bv.y;
    o.z = xv.z + bf2f(fv[2]) + bv.z;
    o.w = xv.w + bf2f(fv[3]) + bv.w;
    ((float4*)(out + gOff))[t] = o;
}

// ---------------------------------------------------------------------------
// LN1 chunk: y[r,:] = bf16( LN(x[bi,(l+SHIFT)%L,:]) * g + b ), fp32 input
// ---------------------------------------------------------------------------
__global__ __launch_bounds__(256, 4) void ln1_kernel(
    const float* __restrict__ x, const float* __restrict__ g,
    const float* __restrict__ bb, u16* __restrict__ y, int rowBase) {
    const int row = rowBase + blockIdx.x;
    const int bi = row >> 12, l = row & 4095;
    const float* src = x + ((size_t)(bi << 12) + ((l + SHIFT_) & 4095)) * 1024;
    const int t = threadIdx.x;
    const int lane = t & 63, wv = t >> 6;

    const float4 u = ((const float4*)src)[t];
    float v[4] = {u.x, u.y, u.z, u.w};
    float sum = 0.f, sq = 0.f;
#pragma unroll
    for (int k = 0; k < 4; ++k) { sum += v[k]; sq += v[k] * v[k]; }
    for (int off = 32; off > 0; off >>= 1) {
        sum += __shfl_down(sum, off);
        sq += __shfl_down(sq, off);
    }
    __shared__ float red[8];
    __shared__ float smu, srs;
    if (lane == 0) { red[wv] = sum; red[4 + wv] = sq; }
    __syncthreads();
    if (t == 0) {
        float s = red[0] + red[1] + red[2] + red[3];
        float q = red[4] + red[5] + red[6] + red[7];
        float mu = s * (1.0f / 1024.0f);
        float var = q * (1.0f / 1024.0f) - mu * mu;
        smu = mu;
        srs = rsqrtf(var + 1e-5f);
    }
    __syncthreads();
    const float mu = smu, rs = srs;
    const float4 gv = ((const float4*)g)[t];
    const float4 bv = ((const float4*)bb)[t];
    u16x4 outv;
    outv[0] = f2bf((v[0] - mu) * rs * gv.x + bv.x);
    outv[1] = f2bf((v[1] - mu) * rs * gv.y + bv.y);
    outv[2] = f2bf((v[2] - mu) * rs * gv.z + bv.z);
    outv[3] = f2bf((v[3] - mu) * rs * gv.w + bv.w);
    ((u16x4*)(y + (size_t)blockIdx.x * 1024))[t] = outv;
}

// ---------------------------------------------------------------------------
// LN2 fused (full M): x2 = x + roll(o2,+32)  (fp32 -> d_out)
//                     z  = bf16( LN(x2)*g + b )
// ---------------------------------------------------------------------------
__global__ __launch_bounds__(256, 4) void ln2_kernel(
    const float* __restrict__ x, const u16* __restrict__ o2,
    const float* __restrict__ g, const float* __restrict__ bb,
    float* __restrict__ x2, u16* __restrict__ z) {
    const int row = blockIdx.x;
    const int bi = row >> 12, l = row & 4095;
    const size_t srcO = (size_t)(bi << 12) + ((l - SHIFT_) & 4095);
    const int t = threadIdx.x;
    const int lane = t & 63, wv = t >> 6;

    const float4 ux = ((const float4*)(x + (size_t)row * 1024))[t];
    const u16x4 uo = ((const u16x4*)(o2 + srcO * 1024))[t];
    float v[4];
    v[0] = ux.x + bf2f(uo[0]);
    v[1] = ux.y + bf2f(uo[1]);
    v[2] = ux.z + bf2f(uo[2]);
    v[3] = ux.w + bf2f(uo[3]);
    float sum = 0.f, sq = 0.f;
#pragma unroll
    for (int k = 0; k < 4; ++k) { sum += v[k]; sq += v[k] * v[k]; }
    float4 x2v = {v[0], v[1], v[2], v[3]};
    ((float4*)(x2 + (size_t)row * 1024))[t] = x2v;

    for (int off = 32; off > 0; off >>= 1) {
        sum += __shfl_down(sum, off);
        sq += __shfl_down(sq, off);
    }
    __shared__ float red[8];
    __shared__ float smu, srs;
    if (lane == 0) { red[wv] = sum; red[4 + wv] = sq; }
    __syncthreads();
    if (t == 0) {
        float s = red[0] + red[1] + red[2] + red[3];
        float q = red[4] + red[5] + red[6] + red[7];
        float mu = s * (1.0f / 1024.0f);
        float var = q * (1.0f / 1024.0f) - mu * mu;
        smu = mu;
        srs = rsqrtf(var + 1e-5f);
    }
    __syncthreads();
    const float mu = smu, rs = srs;
    const float4 gv = ((const float4*)g)[t];
    const float4 bv = ((const float4*)bb)[t];
    u16x4 outv;
    outv[0] = f2bf((v[0] - mu) * rs * gv.x + bv.x);
    outv[1] = f2bf((v[1] - mu) * rs * gv.y + bv.y);
    outv[2] = f2bf((v[2] - mu) * rs * gv.z + bv.z);
    outv[3] = f2bf((v[3] - mu) * rs * gv.w + bv.w);
    ((u16x4*)(z + (size_t)row * 1024))[t] = outv;
}

// ---------------------------------------------------------------------------
// Windowed attention (chunk-local, bf16 in/out): block = (window, head).
// ---------------------------------------------------------------------------
__global__ __launch_bounds__(256, 2) void attn_kernel(
    const u16* __restrict__ qkv, u16* __restrict__ o) {
    __shared__ __align__(16) u16 sQ[64 * 64];  // reused as P
    __shared__ __align__(16) u16 sK[64 * 64];
    __shared__ __align__(16) u16 sV[64 * 64];
    __shared__ float sS[64 * 66];

    const int t = threadIdx.x;
    const int win = blockIdx.x >> 4;
    const int head = blockIdx.x & 15;
    const size_t rowbase = (size_t)win * 64;
    const u16* base = qkv + rowbase * 3072 + head * 64;

    {  // stage Q,K,V via global_load_lds: chunks c = t, t+256
        const int c0 = t, c1 = t + 256;
        const int r0 = c0 >> 3, d0 = (c0 & 7) * 8;
        const int r1 = c1 >> 3, d1 = (c1 & 7) * 8;
        const u16* g0 = base + (size_t)r0 * 3072 + d0;
        const u16* g1 = base + (size_t)r1 * 3072 + d1;
        gload16(g0, &sQ[c0 * 8]);
        gload16(g1, &sQ[c1 * 8]);
        gload16(g0 + 1024, &sK[c0 * 8]);
        gload16(g1 + 1024, &sK[c1 * 8]);
        gload16(g0 + 2048, &sV[c0 * 8]);
        gload16(g1 + 2048, &sV[c1 * 8]);
    }
    __syncthreads();

    const int lane = t & 63, wv = t >> 6;
    const int ln15 = lane & 15, quad = lane >> 4;

    f32x4 accS[4] = {};
#pragma unroll
    for (int kb = 0; kb < 2; ++kb) {
        bf16x8 aF = ldfrag(&sQ[(wv * 16 + ln15) * 64 + kb * 32 + quad * 8]);
#pragma unroll
        for (int jt = 0; jt < 4; ++jt) {
            bf16x8 bF = ldfrag(&sK[(jt * 16 + ln15) * 64 + kb * 32 + quad * 8]);
            accS[jt] = mfma16(aF, bF, accS[jt]);
        }
    }
#pragma unroll
    for (int jt = 0; jt < 4; ++jt)
#pragma unroll
        for (int r = 0; r < 4; ++r)
            sS[(wv * 16 + quad * 4 + r) * 66 + jt * 16 + ln15] =
                accS[jt][r] * 0.125f;
    __syncthreads();

    {
        const int row = t >> 2, part = t & 3;
        const float* sr = &sS[row * 66 + part * 16];
        float vals[16];
        float mx = -1e30f;
#pragma unroll
        for (int i = 0; i < 16; ++i) {
            vals[i] = sr[i];
            mx = fmaxf(mx, vals[i]);
        }
        mx = fmaxf(mx, __shfl_xor(mx, 1));
        mx = fmaxf(mx, __shfl_xor(mx, 2));
        float sum = 0.f;
#pragma unroll
        for (int i = 0; i < 16; ++i) {
            vals[i] = __expf(vals[i] - mx);
            sum += vals[i];
        }
        sum += __shfl_xor(sum, 1);
        sum += __shfl_xor(sum, 2);
        const float inv = 1.0f / sum;
        u16* pr = &sQ[row * 64 + part * 16];
#pragma unroll
        for (int i = 0; i < 16; ++i) pr[i] = f2bf(vals[i] * inv);
    }
    __syncthreads();

    f32x4 accO[4] = {};
#pragma unroll
    for (int kb = 0; kb < 2; ++kb) {
        bf16x8 aF = ldfrag(&sQ[(wv * 16 + ln15) * 64 + kb * 32 + quad * 8]);
#pragma unroll
        for (int dt = 0; dt < 4; ++dt) {
            u16 tmp[8];
#pragma unroll
            for (int j = 0; j < 8; ++j)
                tmp[j] = sV[(kb * 32 + quad * 8 + j) * 64 + dt * 16 + ln15];
            bf16x8 bF;
            __builtin_memcpy(&bF, tmp, 16);
            accO[dt] = mfma16(aF, bF, accO[dt]);
        }
    }
    u16* ob = o + rowbase * 1024 + head * 64;
#pragma unroll
    for (int dt = 0; dt < 4; ++dt)
#pragma unroll
        for (int r = 0; r < 4; ++r) {
            const int q = wv * 16 + quad * 4 + r;
            const int d = dt * 16 + ln15;
            ob[(size_t)q * 1024 + d] = f2bf(accO[dt][r]);
        }
}

// ---------------------------------------------------------------------------
extern "C" void kernel_launch(void* const* d_in, const int* in_sizes, int n_in,
                              void* d_out, int out_size, void* d_ws,
                              size_t ws_size, hipStream_t stream) {
    (void)in_sizes; (void)n_in; (void)out_size; (void)ws_size;
    const float* x = (const float*)d_in[0];
    const float* ln1_g = (const float*)d_in[1];
    const float* ln1_b = (const float*)d_in[2];
    const float* in_proj_w = (const float*)d_in[3];
    const float* in_proj_b = (const float*)d_in[4];
    const float* out_proj_w = (const float*)d_in[5];
    const float* out_proj_b = (const float*)d_in[6];
    const float* ln2_g = (const float*)d_in[7];
    const float* ln2_b = (const float*)d_in[8];
    const float* w1 = (const float*)d_in[9];
    const float* b1 = (const float*)d_in[10];
    const float* w2 = (const float*)d_in[11];
    const float* b2 = (const float*)d_in[12];
    float* out = (float*)d_out;

    // Workspace layout (128 MB high-water; round-1 evidence: ws >= 160 MB):
    //   [  0,  8M) w1 bf16 (persist)     [  8, 16M) w2 bf16 (persist)
    //   [ 16, 22M) inproj bf16 (A)       [ 22, 24M) outproj bf16 (A)
    //   [ 24, 72M) qkv_c bf16 (A, 8192 x 3072)
    //   [ 72,104M) o2 bf16 full M (A -> B)
    //   [ 16, 48M) z bf16 full M (B -> C; overlays dead inproj/outproj/qkv)
    //   [ 48,112M) h bf16 chunk (C, 8192 x 4096; overlays dead qkv tail/o2)
    //   [112,128M) ff_c bf16 chunk (C, 8192 x 1024)
    // d_out doubles as scratch: phase A qin [0,16M) + o_full [16,48M) bf16;
    // phase B writes x2 fp32 over all of d_out; add_kernel RMWs it to final.
    char* ws = (char*)d_ws;
    const size_t MB = 1024 * 1024;
    u16* wb_w1 = (u16*)(ws + 0 * MB);
    u16* wb_w2 = (u16*)(ws + 8 * MB);
    u16* wb_inproj = (u16*)(ws + 16 * MB);
    u16* wb_outproj = (u16*)(ws + 22 * MB);
    u16* qkv_c = (u16*)(ws + 24 * MB);
    u16* o2 = (u16*)(ws + 72 * MB);
    u16* z = (u16*)(ws + 16 * MB);
    u16* h_buf = (u16*)(ws + 48 * MB);
    u16* ff_c = (u16*)(ws + 112 * MB);

    u16* qin = (u16*)d_out;                        // [0,16M) of d_out
    u16* o_full = (u16*)((char*)d_out + 16 * MB);  // [16,48M) of d_out
    float* x2 = out;

    const int M = B_ * L_;  // 16384

    // Prologue: weights fp32 -> bf16
    cvt_kernel<<<(FF_ * H_ / 4 + 255) / 256, 256, 0, stream>>>(
        w1, wb_w1, FF_ * H_ / 4);
    cvt_kernel<<<(H_ * FF_ / 4 + 255) / 256, 256, 0, stream>>>(
        w2, wb_w2, H_ * FF_ / 4);
    cvt_kernel<<<(3 * H_ * H_ / 4 + 255) / 256, 256, 0, stream>>>(
        in_proj_w, wb_inproj, 3 * H_ * H_ / 4);
    cvt_kernel<<<(H_ * H_ / 4 + 255) / 256, 256, 0, stream>>>(
        out_proj_w, wb_outproj, H_ * H_ / 4);

    // Phase A: ln1 -> qkv proj -> windowed attn (2 chunks of 8192 rows)
    for (int c = 0; c < 2; ++c) {
        const int rowBase = c * MCA_;
        ln1_kernel<<<MCA_, 256, 0, stream>>>(x, ln1_g, ln1_b, qin, rowBase);
        gemm_bt<0, 1><<<dim3(3 * H_ / 128, MCA_ / 128), 256, 0, stream>>>(
            qin, wb_inproj, H_, in_proj_b, qkv_c, MCA_, 3 * H_, H_);
        attn_kernel<<<(MCA_ / W_) * NH_, 256, 0, stream>>>(
            qkv_c, o_full + (size_t)rowBase * H_);
    }
    // out_proj over full M (grid 8 x 128 = 1024 blocks)
    gemm_bt<0, 1><<<dim3(H_ / 128, M / 128), 256, 0, stream>>>(
        o_full, wb_outproj, H_, out_proj_b, o2, M, H_, H_);

    // Phase B: x2 = x + roll(o2,+32) (fp32 -> d_out), z = bf16(LN2(x2))
    ln2_kernel<<<M, 256, 0, stream>>>(x, o2, ln2_g, ln2_b, x2, z);

    // Phase C: FFN in 2 row-chunks of 8192; all-bf16 GEMMs + coalesced add.
    for (int c = 0; c < 2; ++c) {
        const int rowBase = c * MCF_;
        const size_t off = (size_t)rowBase * H_;
        // FF1: h = gelu(z_c @ w1^T + b1)        grid (32,64) = 2048 blocks
        gemm_bt<1, 1><<<dim3(FF_ / 128, MCF_ / 128), 256, 0, stream>>>(
            z + off, wb_w1, H_, b1, h_buf, MCF_, FF_, H_);
        // FF2: ff = h @ w2^T (no bias)          grid (8,64) = 512 blocks
        gemm_bt<0, 0><<<dim3(H_ / 128, MCF_ / 128), 256, 0, stream>>>(
            h_buf, wb_w2, FF_, nullptr, ff_c, MCF_, H_, FF_);
        // out = x2 + ff + b2                    fully-coalesced fp32 pass
        add_kernel<<<MCF_, 256, 0, stream>>>(ff_c, b2, out, rowBase);
    }
}